// Round 1
// baseline (6372.516 us; speedup 1.0000x reference)
//
#include <hip/hip_runtime.h>
#include <math.h>

// Problem constants: B=64, C=512, S=512, E=257, LK=128, HK=129.
// Key insight: high_x is dead code in the reference (empty slice), so only
// low_x = attn(low,low,low)+attn(low,high,low) is needed.
//
// Pipeline:
//  1. build Bf (512x514, ld 516): DFT matrix (cos | -sin) * 1/sqrt(512)
//  2. build Bp (514x1028): complex projection [[l1r|l1i],[-l1i|l1r]] blocks for low & high
//  3. build iD (514x512): inverse rfft matrix (Hermitian-symmetric coefficients)
//  4. gemm: xf = x @ Bf           (rows [Xr(257)|Xi(257)], ld 520)
//  5. gemm: LH = xf @ Bp          (rows [lowr|lowi|highr|highi], ld 1028) + bias+relu
//  6. fused flash-style complex attention -> OX (reuses xf buffer, ld 520)
//  7. gemm: out = OX @ iD
//
// Workspace: ~207.2 MB of fp32.

#define LD_XF 520
#define LD_LH 1028
#define LD_BF 516

// ---------------- prep kernels ----------------

__global__ __launch_bounds__(256) void build_dft_kernel(float* __restrict__ Bf) {
  int idx = blockIdx.x * 256 + threadIdx.x;
  const int total = 512 * 514;
  if (idx >= total) return;
  int n = idx / 514;
  int col = idx - n * 514;
  int k = (col < 257) ? col : col - 257;
  int m = (n * k) & 511;
  float ang = (float)m * 0.0122718463030851f;   // 2*pi/512
  const float sc = 0.0441941738241592f;         // 1/sqrt(512)
  float v = (col < 257) ? cosf(ang) * sc : -sinf(ang) * sc;
  Bf[(size_t)n * LD_BF + col] = v;
}

__global__ __launch_bounds__(256) void build_proj_kernel(
    const float* __restrict__ l1r, const float* __restrict__ l1i,
    const float* __restrict__ h1r, const float* __restrict__ h1i,
    float* __restrict__ Bp) {
  int idx = blockIdx.x * 256 + threadIdx.x;
  const int total = 514 * 1028;
  if (idx >= total) return;
  int j = idx / 1028;
  int col = idx - j * 1028;
  float v = 0.0f;
  if (j < 128) {                    // Xr[k], k=j -> low outputs
    int k = j;
    if (col < 257) v = l1r[k * 257 + col];
    else if (col < 514) v = l1i[k * 257 + (col - 257)];
  } else if (j < 257) {             // Xr[128+k], k=j-128 -> high outputs
    int k = j - 128;
    if (col >= 514 && col < 771) v = h1r[k * 257 + (col - 514)];
    else if (col >= 771) v = h1i[k * 257 + (col - 771)];
  } else if (j < 385) {             // Xi[k], k=j-257 -> low outputs
    int k = j - 257;
    if (col < 257) v = -l1i[k * 257 + col];
    else if (col < 514) v = l1r[k * 257 + (col - 257)];
  } else {                          // Xi[128+k], k=j-385 -> high outputs
    int k = j - 385;
    if (col >= 514 && col < 771) v = -h1i[k * 257 + (col - 514)];
    else if (col >= 771) v = h1r[k * 257 + (col - 771)];
  }
  Bp[(size_t)j * 1028 + col] = v;
}

__global__ __launch_bounds__(256) void build_idft_kernel(float* __restrict__ iD) {
  int idx = blockIdx.x * 256 + threadIdx.x;
  const int total = 514 * 512;
  if (idx >= total) return;
  int kc = idx / 512;
  int n = idx - kc * 512;
  int k = (kc < 257) ? kc : kc - 257;
  int m = (n * k) & 511;
  float ang = (float)m * 0.0122718463030851f;
  const float sc = 0.0441941738241592f;
  float c = (k == 0 || k == 256) ? 1.0f : 2.0f;
  float v = (kc < 257) ? c * sc * cosf(ang) : -c * sc * sinf(ang);
  iD[(size_t)kc * 512 + n] = v;
}

__global__ __launch_bounds__(256) void bias_relu_kernel(
    float* __restrict__ LH,
    const float* __restrict__ lbr, const float* __restrict__ lbi,
    const float* __restrict__ hbr, const float* __restrict__ hbi) {
  int row = blockIdx.x;
  float* p = LH + (size_t)row * LD_LH;
  for (int c = threadIdx.x; c < 1028; c += 256) {
    float bv;
    if (c < 257) bv = lbr[c];
    else if (c < 514) bv = lbi[c - 257];
    else if (c < 771) bv = hbr[c - 514];
    else bv = hbi[c - 771];
    float v = p[c] + bv;
    p[c] = v > 0.0f ? v : 0.0f;
  }
}

// ---------------- generic fp32 tiled GEMM: C = A(MxK) @ B(KxN) ----------------
// 64x64 tile, BK=16, 256 threads, 4x4 per thread. M must be a multiple of 64.

__global__ __launch_bounds__(256) void gemm_f32(
    const float* __restrict__ A, int lda,
    const float* __restrict__ Bm, int ldb,
    float* __restrict__ Cm, int ldc,
    int M, int N, int K) {
  __shared__ __align__(16) float As[16][72];
  __shared__ __align__(16) float Bs[16][72];
  int t = threadIdx.x;
  int tx = t & 15;
  int ty = t >> 4;
  int row0 = blockIdx.y * 64;
  int col0 = blockIdx.x * 64;
  float acc[4][4] = {{0.f}};

  for (int k0 = 0; k0 < K; k0 += 16) {
    // A tile -> As[k][m] (transposed)
    {
      int m = t >> 2;
      int k4 = (t & 3) * 4;
      const float* src = A + (size_t)(row0 + m) * lda + k0 + k4;
      float vx = 0.f, vy = 0.f, vz = 0.f, vw = 0.f;
      if (k0 + k4 + 3 < K) {
        float4 v = *(const float4*)src;
        vx = v.x; vy = v.y; vz = v.z; vw = v.w;
      } else {
        if (k0 + k4 + 0 < K) vx = src[0];
        if (k0 + k4 + 1 < K) vy = src[1];
        if (k0 + k4 + 2 < K) vz = src[2];
        if (k0 + k4 + 3 < K) vw = src[3];
      }
      As[k4 + 0][m] = vx; As[k4 + 1][m] = vy;
      As[k4 + 2][m] = vz; As[k4 + 3][m] = vw;
    }
    // B tile -> Bs[k][n]
    {
      int kb = t >> 4;
      int n4 = (t & 15) * 4;
      float4 v = {0.f, 0.f, 0.f, 0.f};
      if (k0 + kb < K) {
        const float* src = Bm + (size_t)(k0 + kb) * ldb + col0 + n4;
        if (col0 + n4 + 3 < N) {
          v = *(const float4*)src;
        } else {
          if (col0 + n4 + 0 < N) v.x = src[0];
          if (col0 + n4 + 1 < N) v.y = src[1];
          if (col0 + n4 + 2 < N) v.z = src[2];
          if (col0 + n4 + 3 < N) v.w = src[3];
        }
      }
      *(float4*)&Bs[kb][n4] = v;
    }
    __syncthreads();
#pragma unroll
    for (int kk = 0; kk < 16; ++kk) {
      float4 av = *(const float4*)&As[kk][ty * 4];
      float4 bv = *(const float4*)&Bs[kk][tx * 4];
      float a0 = av.x, a1 = av.y, a2 = av.z, a3 = av.w;
      float b0 = bv.x, b1 = bv.y, b2 = bv.z, b3 = bv.w;
      acc[0][0] += a0 * b0; acc[0][1] += a0 * b1; acc[0][2] += a0 * b2; acc[0][3] += a0 * b3;
      acc[1][0] += a1 * b0; acc[1][1] += a1 * b1; acc[1][2] += a1 * b2; acc[1][3] += a1 * b3;
      acc[2][0] += a2 * b0; acc[2][1] += a2 * b1; acc[2][2] += a2 * b2; acc[2][3] += a2 * b3;
      acc[3][0] += a3 * b0; acc[3][1] += a3 * b1; acc[3][2] += a3 * b2; acc[3][3] += a3 * b3;
    }
    __syncthreads();
  }
#pragma unroll
  for (int i = 0; i < 4; ++i) {
    int r = row0 + ty * 4 + i;
#pragma unroll
    for (int j = 0; j < 4; ++j) {
      int c = col0 + tx * 4 + j;
      if (c < N) Cm[(size_t)r * ldc + c] = acc[i][j];
    }
  }
}

// ---------------- fused complex attention ----------------
// low_x = attn(low, low, low) + attn(low, high, low)
// Per block: one batch b, 16 Q-rows. Online softmax (separate m,l for real & imag).
// LDS: Q[16][516] (interleaved re/im), KV[16][516], Ss (exp weights), stats. ~68.5 KB.

__global__ __launch_bounds__(256) void attn_fused(
    const float* __restrict__ LH, float* __restrict__ OX) {
  int b = blockIdx.y;
  int rt = blockIdx.x;
  int t = threadIdx.x;
  int r = t >> 4;       // 0..15: Q row within tile
  int lane = t & 15;    // 0..15: j (S phase) / e-lane (PV phase)
  const float scale = 1.0f / sqrtf(257.0f);

  __shared__ __align__(16) float Q[16][516];
  __shared__ __align__(16) float KV[16][516];
  __shared__ float Ss[2][16][16];
  __shared__ float Mrow[2][16], Lrow[2][16], Fac[2][16];

  const float* bbase = LH + (size_t)b * 512 * LD_LH;

  // load Q tile (low rows rt*16..rt*16+15), interleaved re/im
  for (int idx = t; idx < 16 * 257; idx += 256) {
    int rr = idx / 257;
    int e = idx - rr * 257;
    const float* src = bbase + (size_t)(rt * 16 + rr) * LD_LH;
    Q[rr][2 * e] = src[e];
    Q[rr][2 * e + 1] = src[257 + e];
  }

  float outr[16], outi[16], outr16 = 0.f, outi16 = 0.f;
#pragma unroll
  for (int s = 0; s < 16; ++s) { outr[s] = 0.f; outi[s] = 0.f; }

  for (int pass = 0; pass < 2; ++pass) {
    int koff = pass ? 514 : 0;  // K = low (pass 0) or high (pass 1)
    float arr[16], ari[16], air[16], aii[16];
    float t_arr = 0.f, t_ari = 0.f, t_air = 0.f, t_aii = 0.f;
#pragma unroll
    for (int s = 0; s < 16; ++s) { arr[s] = 0.f; ari[s] = 0.f; air[s] = 0.f; aii[s] = 0.f; }
    __syncthreads();  // pass0: Q load done; pass1: finalize reads of Lrow done
    if (t < 32) {
      Mrow[t & 1][t >> 1] = -1e30f;
      Lrow[t & 1][t >> 1] = 0.f;
    }

    for (int jt = 0; jt < 32; ++jt) {
      __syncthreads();  // previous PV readers of KV/Ss done
      // load K tile rows jt*16.., interleaved
      for (int idx = t; idx < 16 * 257; idx += 256) {
        int rr = idx / 257;
        int e = idx - rr * 257;
        const float* src = bbase + (size_t)(jt * 16 + rr) * LD_LH + koff;
        KV[rr][2 * e] = src[e];
        KV[rr][2 * e + 1] = src[257 + e];
      }
      __syncthreads();
      // S phase: thread (r, lane) computes complex dot Q[r] . K[lane]
      {
        float sr = 0.f, si = 0.f;
        const float* qrow = &Q[r][0];
        const float* krow = &KV[lane][0];
#pragma unroll 4
        for (int e2 = 0; e2 < 512; e2 += 4) {
          float4 q = *(const float4*)(qrow + e2);
          float4 k = *(const float4*)(krow + e2);
          sr += q.x * k.x - q.y * k.y;
          si += q.x * k.y + q.y * k.x;
          sr += q.z * k.z - q.w * k.w;
          si += q.z * k.w + q.w * k.z;
        }
        {
          float qx = qrow[512], qy = qrow[513];
          float kx = krow[512], ky = krow[513];
          sr += qx * kx - qy * ky;
          si += qx * ky + qy * kx;
        }
        Ss[0][r][lane] = sr * scale;
        Ss[1][r][lane] = si * scale;
      }
      __syncthreads();
      // softmax bookkeeping (t<32); meanwhile V reload for pass 1
      if (t < 32) {
        int comp = t & 1, row = t >> 1;
        float m_old = Mrow[comp][row];
        float l_old = Lrow[comp][row];
        float tmax = -1e30f;
#pragma unroll
        for (int j = 0; j < 16; ++j) tmax = fmaxf(tmax, Ss[comp][row][j]);
        float m_new = fmaxf(m_old, tmax);
        float fac = __expf(m_old - m_new);
        float sum = 0.f;
#pragma unroll
        for (int j = 0; j < 16; ++j) {
          float u = __expf(Ss[comp][row][j] - m_new);
          Ss[comp][row][j] = u;
          sum += u;
        }
        Mrow[comp][row] = m_new;
        Lrow[comp][row] = l_old * fac + sum;
        Fac[comp][row] = fac;
      }
      if (pass == 1) {  // V = low rows jt*16.. (overwrite KV; safe after S sync)
        for (int idx = t; idx < 16 * 257; idx += 256) {
          int rr = idx / 257;
          int e = idx - rr * 257;
          const float* src = bbase + (size_t)(jt * 16 + rr) * LD_LH;
          KV[rr][2 * e] = src[e];
          KV[rr][2 * e + 1] = src[257 + e];
        }
      }
      __syncthreads();
      // PV accumulate: thread (r, lane) handles e = s*16+lane (s<16) + shared tail e=256
      {
        float fr = Fac[0][r], fi = Fac[1][r];
#pragma unroll
        for (int s = 0; s < 16; ++s) { arr[s] *= fr; ari[s] *= fr; air[s] *= fi; aii[s] *= fi; }
        t_arr *= fr; t_ari *= fr; t_air *= fi; t_aii *= fi;
        for (int j = 0; j < 16; ++j) {
          float ur = Ss[0][r][j], ui = Ss[1][r][j];
          const float* vrow = &KV[j][0];
#pragma unroll
          for (int s = 0; s < 16; ++s) {
            float2 v = *(const float2*)(vrow + 2 * (s * 16 + lane));
            arr[s] += ur * v.x; ari[s] += ur * v.y;
            air[s] += ui * v.x; aii[s] += ui * v.y;
          }
          float vx = vrow[512], vy = vrow[513];
          t_arr += ur * vx; t_ari += ur * vy;
          t_air += ui * vx; t_aii += ui * vy;
        }
      }
    }
    // finalize this pass (Lrow stable since last sync)
    {
      float invLr = 1.0f / Lrow[0][r];
      float invLi = 1.0f / Lrow[1][r];
#pragma unroll
      for (int s = 0; s < 16; ++s) {
        outr[s] += arr[s] * invLr - aii[s] * invLi;
        outi[s] += ari[s] * invLr + air[s] * invLi;
      }
      outr16 += t_arr * invLr - t_aii * invLi;
      outi16 += t_ari * invLr + t_air * invLi;
    }
  }

  // write OX row (ld 520): [re(257) | im(257)]
  float* orow = OX + (size_t)(b * 512 + rt * 16 + r) * LD_XF;
#pragma unroll
  for (int s = 0; s < 16; ++s) {
    int e = s * 16 + lane;
    orow[e] = outr[s];
    orow[257 + e] = outi[s];
  }
  if (lane == 0) {
    orow[256] = outr16;
    orow[513] = outi16;
  }
}

// ---------------- launch ----------------

extern "C" void kernel_launch(void* const* d_in, const int* in_sizes, int n_in,
                              void* d_out, int out_size, void* d_ws, size_t ws_size,
                              hipStream_t stream) {
  const float* x   = (const float*)d_in[0];
  const float* l1r = (const float*)d_in[1];
  const float* l1i = (const float*)d_in[2];
  const float* h1r = (const float*)d_in[3];
  const float* h1i = (const float*)d_in[4];
  const float* lbr = (const float*)d_in[5];
  const float* lbi = (const float*)d_in[6];
  const float* hbr = (const float*)d_in[7];
  const float* hbi = (const float*)d_in[8];
  float* out = (float*)d_out;

  float* ws = (float*)d_ws;
  size_t off = 0;
  float* xf = ws + off; off += (size_t)32768 * LD_XF;   // also reused as OX
  float* LH = ws + off; off += (size_t)32768 * LD_LH;
  float* Bf = ws + off; off += (size_t)512 * LD_BF;
  float* Bp = ws + off; off += (size_t)514 * 1028;
  float* iD = ws + off; off += (size_t)514 * 512;
  // total: 51,780,616 floats = 207.1 MB (must be <= ws_size)

  build_dft_kernel<<<(512 * 514 + 255) / 256, 256, 0, stream>>>(Bf);
  build_proj_kernel<<<(514 * 1028 + 255) / 256, 256, 0, stream>>>(l1r, l1i, h1r, h1i, Bp);
  build_idft_kernel<<<(514 * 512 + 255) / 256, 256, 0, stream>>>(iD);

  // rfft: xf = x @ Bf
  gemm_f32<<<dim3((514 + 63) / 64, 32768 / 64), 256, 0, stream>>>(
      x, 512, Bf, LD_BF, xf, LD_XF, 32768, 514, 512);
  // projections: LH = xf @ Bp
  gemm_f32<<<dim3((1028 + 63) / 64, 32768 / 64), 256, 0, stream>>>(
      xf, LD_XF, Bp, 1028, LH, LD_LH, 32768, 1028, 514);
  bias_relu_kernel<<<32768, 256, 0, stream>>>(LH, lbr, lbi, hbr, hbi);
  // attention -> OX (= xf buffer)
  attn_fused<<<dim3(32, 64), 256, 0, stream>>>(LH, xf);
  // irfft: out = OX @ iD
  gemm_f32<<<dim3(512 / 64, 32768 / 64), 256, 0, stream>>>(
      xf, LD_XF, iD, 512, out, 512, 32768, 512, 514);
}

// Round 2
// 3496.353 us; speedup vs baseline: 1.8226x; 1.8226x over previous
//
#include <hip/hip_runtime.h>
#include <math.h>

// Problem constants: B=64, C=512, S=512, E=257, LK=128, HK=129.
// high_x is dead code in the reference (empty slice): only
// low_x = attn(low,low,low)+attn(low,high,low) is needed.
//
// Pipeline:
//  1. build Bf (512x514): DFT matrix (cos | -sin) / sqrt(512)
//  2. build Bp (514x1028): complex projection blocks for low & high
//  3. build iD (514x512): inverse rfft matrix (Hermitian coefficients)
//  4. gemm: xf = x @ Bf           (rows [Xr|Xi], ld 520)
//  5. gemm: LH = xf @ Bp          (rows [lowr|lowi|highr|highi], ld 1028) + bias+relu
//  6. MFMA f16 flash-style complex attention -> OX (reuses xf buffer)
//  7. gemm: out = OX @ iD

#define LD_XF 520
#define LD_LH 1028
#define LD_BF 516

typedef __attribute__((ext_vector_type(4))) _Float16 f16x4;
typedef __attribute__((ext_vector_type(8))) _Float16 f16x8;
typedef __attribute__((ext_vector_type(4))) float f32x4;

// ---------------- prep kernels ----------------

__global__ __launch_bounds__(256) void build_dft_kernel(float* __restrict__ Bf) {
  int idx = blockIdx.x * 256 + threadIdx.x;
  const int total = 512 * 514;
  if (idx >= total) return;
  int n = idx / 514;
  int col = idx - n * 514;
  int k = (col < 257) ? col : col - 257;
  int m = (n * k) & 511;
  float ang = (float)m * 0.0122718463030851f;   // 2*pi/512
  const float sc = 0.0441941738241592f;         // 1/sqrt(512)
  float v = (col < 257) ? cosf(ang) * sc : -sinf(ang) * sc;
  Bf[(size_t)n * LD_BF + col] = v;
}

__global__ __launch_bounds__(256) void build_proj_kernel(
    const float* __restrict__ l1r, const float* __restrict__ l1i,
    const float* __restrict__ h1r, const float* __restrict__ h1i,
    float* __restrict__ Bp) {
  int idx = blockIdx.x * 256 + threadIdx.x;
  const int total = 514 * 1028;
  if (idx >= total) return;
  int j = idx / 1028;
  int col = idx - j * 1028;
  float v = 0.0f;
  if (j < 128) {
    int k = j;
    if (col < 257) v = l1r[k * 257 + col];
    else if (col < 514) v = l1i[k * 257 + (col - 257)];
  } else if (j < 257) {
    int k = j - 128;
    if (col >= 514 && col < 771) v = h1r[k * 257 + (col - 514)];
    else if (col >= 771) v = h1i[k * 257 + (col - 771)];
  } else if (j < 385) {
    int k = j - 257;
    if (col < 257) v = -l1i[k * 257 + col];
    else if (col < 514) v = l1r[k * 257 + (col - 257)];
  } else {
    int k = j - 385;
    if (col >= 514 && col < 771) v = -h1i[k * 257 + (col - 514)];
    else if (col >= 771) v = h1r[k * 257 + (col - 771)];
  }
  Bp[(size_t)j * 1028 + col] = v;
}

__global__ __launch_bounds__(256) void build_idft_kernel(float* __restrict__ iD) {
  int idx = blockIdx.x * 256 + threadIdx.x;
  const int total = 514 * 512;
  if (idx >= total) return;
  int kc = idx / 512;
  int n = idx - kc * 512;
  int k = (kc < 257) ? kc : kc - 257;
  int m = (n * k) & 511;
  float ang = (float)m * 0.0122718463030851f;
  const float sc = 0.0441941738241592f;
  float c = (k == 0 || k == 256) ? 1.0f : 2.0f;
  float v = (kc < 257) ? c * sc * cosf(ang) : -c * sc * sinf(ang);
  iD[(size_t)kc * 512 + n] = v;
}

__global__ __launch_bounds__(256) void bias_relu_kernel(
    float* __restrict__ LH,
    const float* __restrict__ lbr, const float* __restrict__ lbi,
    const float* __restrict__ hbr, const float* __restrict__ hbi) {
  int row = blockIdx.x;
  float* p = LH + (size_t)row * LD_LH;
  for (int c = threadIdx.x; c < 1028; c += 256) {
    float bv;
    if (c < 257) bv = lbr[c];
    else if (c < 514) bv = lbi[c - 257];
    else if (c < 771) bv = hbr[c - 514];
    else bv = hbi[c - 771];
    float v = p[c] + bv;
    p[c] = v > 0.0f ? v : 0.0f;
  }
}

// ---------------- generic fp32 tiled GEMM: C = A(MxK) @ B(KxN) ----------------

__global__ __launch_bounds__(256) void gemm_f32(
    const float* __restrict__ A, int lda,
    const float* __restrict__ Bm, int ldb,
    float* __restrict__ Cm, int ldc,
    int M, int N, int K) {
  __shared__ __align__(16) float As[16][72];
  __shared__ __align__(16) float Bs[16][72];
  int t = threadIdx.x;
  int tx = t & 15;
  int ty = t >> 4;
  int row0 = blockIdx.y * 64;
  int col0 = blockIdx.x * 64;
  float acc[4][4] = {{0.f}};

  for (int k0 = 0; k0 < K; k0 += 16) {
    {
      int m = t >> 2;
      int k4 = (t & 3) * 4;
      const float* src = A + (size_t)(row0 + m) * lda + k0 + k4;
      float vx = 0.f, vy = 0.f, vz = 0.f, vw = 0.f;
      if (k0 + k4 + 3 < K) {
        float4 v = *(const float4*)src;
        vx = v.x; vy = v.y; vz = v.z; vw = v.w;
      } else {
        if (k0 + k4 + 0 < K) vx = src[0];
        if (k0 + k4 + 1 < K) vy = src[1];
        if (k0 + k4 + 2 < K) vz = src[2];
        if (k0 + k4 + 3 < K) vw = src[3];
      }
      As[k4 + 0][m] = vx; As[k4 + 1][m] = vy;
      As[k4 + 2][m] = vz; As[k4 + 3][m] = vw;
    }
    {
      int kb = t >> 4;
      int n4 = (t & 15) * 4;
      float4 v = {0.f, 0.f, 0.f, 0.f};
      if (k0 + kb < K) {
        const float* src = Bm + (size_t)(k0 + kb) * ldb + col0 + n4;
        if (col0 + n4 + 3 < N) {
          v = *(const float4*)src;
        } else {
          if (col0 + n4 + 0 < N) v.x = src[0];
          if (col0 + n4 + 1 < N) v.y = src[1];
          if (col0 + n4 + 2 < N) v.z = src[2];
          if (col0 + n4 + 3 < N) v.w = src[3];
        }
      }
      *(float4*)&Bs[kb][n4] = v;
    }
    __syncthreads();
#pragma unroll
    for (int kk = 0; kk < 16; ++kk) {
      float4 av = *(const float4*)&As[kk][ty * 4];
      float4 bv = *(const float4*)&Bs[kk][tx * 4];
      float a0 = av.x, a1 = av.y, a2 = av.z, a3 = av.w;
      float b0 = bv.x, b1 = bv.y, b2 = bv.z, b3 = bv.w;
      acc[0][0] += a0 * b0; acc[0][1] += a0 * b1; acc[0][2] += a0 * b2; acc[0][3] += a0 * b3;
      acc[1][0] += a1 * b0; acc[1][1] += a1 * b1; acc[1][2] += a1 * b2; acc[1][3] += a1 * b3;
      acc[2][0] += a2 * b0; acc[2][1] += a2 * b1; acc[2][2] += a2 * b2; acc[2][3] += a2 * b3;
      acc[3][0] += a3 * b0; acc[3][1] += a3 * b1; acc[3][2] += a3 * b2; acc[3][3] += a3 * b3;
    }
    __syncthreads();
  }
#pragma unroll
  for (int i = 0; i < 4; ++i) {
    int r = row0 + ty * 4 + i;
#pragma unroll
    for (int j = 0; j < 4; ++j) {
      int c = col0 + tx * 4 + j;
      if (c < N) Cm[(size_t)r * ldc + c] = acc[i][j];
    }
  }
}

// ---------------- MFMA f16 fused complex attention ----------------
// Block = (batch b, 16 Q-rows). 4 waves. j-chunk = 16 K-rows, 64 chunk-iters
// (2 passes x 32). Each wave redundantly computes the full 16x16 complex score
// tile (MFMA 16x16x32, K-dim = e padded to 288), does online softmax with
// quad shuffles (stats in registers: C-layout row = quad*4+reg), transposes
// P via a per-wave LDS buffer, then PV (MFMA 16x16x16) over its private
// e-tile slice (5/4/4/4 of 17 tiles).
//
// LDS (f16): sQ[2][16][296] | sK[2][16][296] | sVT[2][272][20] | sP[4][2][16][20]
//          = 9472 + 9472 + 10880 + 2560 = 32384 halves = 64768 B -> 2 blocks/CU.

__global__ __launch_bounds__(256, 2) void attn_mfma(
    const float* __restrict__ LH, float* __restrict__ OX) {
  int b = blockIdx.y;
  int rt = blockIdx.x;
  int t = threadIdx.x;
  int w = t >> 6;
  int L = t & 63;
  int q = L >> 4;    // quad id 0..3
  int lc = L & 15;   // lane col 0..15

  __shared__ __align__(16) _Float16 smem[32384];
  _Float16* sQ = smem;                // [comp][row16][296]
  _Float16* sK = smem + 9472;         // [comp][row16][296]
  _Float16* sVT = smem + 18944;       // [comp][e272][20]
  _Float16* sP = smem + 29824;        // [wave][comp][m16][20]

  // zero sQ/sK/sVT (covers the e>=257 zero padding; done once)
  {
    uint4* z = (uint4*)smem;
    for (int i = t; i < 29824 / 8; i += 256) z[i] = uint4{0u, 0u, 0u, 0u};
  }
  __syncthreads();

  const float* bbase = LH + (size_t)b * 512 * LD_LH;
  const float SCALE = 0.0623782910f;  // 1/sqrt(257), folded into Q

  // stage Q tile (scaled)
  {
    int rr = t >> 4, ecol = t & 15;
    const float* qrow = bbase + (size_t)(rt * 16 + rr) * LD_LH;
#pragma unroll
    for (int s = 0; s < 17; ++s) {
      int e = ecol + 16 * s;
      if (e < 257) {
        sQ[rr * 296 + e] = (_Float16)(qrow[e] * SCALE);
        sQ[16 * 296 + rr * 296 + e] = (_Float16)(qrow[257 + e] * SCALE);
      }
    }
  }

  const int t0s[4] = {0, 5, 9, 13};
  const int nts[4] = {5, 4, 4, 4};
  int t0 = t0s[w], nt = nts[w];

  f32x4 outR[5], outI[5];
#pragma unroll
  for (int i = 0; i < 5; ++i) {
    outR[i] = f32x4{0.f, 0.f, 0.f, 0.f};
    outI[i] = f32x4{0.f, 0.f, 0.f, 0.f};
  }

  for (int pass = 0; pass < 2; ++pass) {
    int koff = pass ? 514 : 0;
    f32x4 accRR[5], accRI[5], accIR[5], accII[5];
    float m_r[4], l_r[4], m_i[4], l_i[4], fac_r[4], fac_i[4];
#pragma unroll
    for (int i = 0; i < 5; ++i) {
      accRR[i] = f32x4{0.f, 0.f, 0.f, 0.f};
      accRI[i] = f32x4{0.f, 0.f, 0.f, 0.f};
      accIR[i] = f32x4{0.f, 0.f, 0.f, 0.f};
      accII[i] = f32x4{0.f, 0.f, 0.f, 0.f};
    }
#pragma unroll
    for (int r = 0; r < 4; ++r) {
      m_r[r] = -3.0e38f; l_r[r] = 0.f;
      m_i[r] = -3.0e38f; l_i[r] = 0.f;
    }

    for (int jt = 0; jt < 32; ++jt) {
      __syncthreads();  // all waves done reading previous K/VT
      // ---- stage K chunk (rows jt*16..+15) and V (transposed) ----
      {
        int rr = t >> 4, ecol = t & 15;
        const float* krow = bbase + (size_t)(jt * 16 + rr) * LD_LH + koff;
        const float* vrow = bbase + (size_t)(jt * 16 + rr) * LD_LH;
#pragma unroll
        for (int s = 0; s < 17; ++s) {
          int e = ecol + 16 * s;
          if (e < 257) {
            float kr = krow[e], ki = krow[257 + e];
            sK[rr * 296 + e] = (_Float16)kr;
            sK[16 * 296 + rr * 296 + e] = (_Float16)ki;
            float vr, vi;
            if (pass == 0) { vr = kr; vi = ki; }
            else { vr = vrow[e]; vi = vrow[257 + e]; }
            sVT[e * 20 + rr] = (_Float16)vr;
            sVT[272 * 20 + e * 20 + rr] = (_Float16)vi;
          }
        }
      }
      __syncthreads();  // staged data visible

      // ---- scores: 4 independent MFMA chains over 9 e-chunks ----
      f32x4 sRR = f32x4{0.f, 0.f, 0.f, 0.f};
      f32x4 sRI = f32x4{0.f, 0.f, 0.f, 0.f};
      f32x4 sIR = f32x4{0.f, 0.f, 0.f, 0.f};
      f32x4 sII = f32x4{0.f, 0.f, 0.f, 0.f};
#pragma unroll
      for (int ec = 0; ec < 9; ++ec) {
        int fo = ec * 32 + q * 8;
        f16x8 aQr = *(const f16x8*)(sQ + lc * 296 + fo);
        f16x8 aQi = *(const f16x8*)(sQ + 16 * 296 + lc * 296 + fo);
        f16x8 bKr = *(const f16x8*)(sK + lc * 296 + fo);
        f16x8 bKi = *(const f16x8*)(sK + 16 * 296 + lc * 296 + fo);
        sRR = __builtin_amdgcn_mfma_f32_16x16x32_f16(aQr, bKr, sRR, 0, 0, 0);
        sII = __builtin_amdgcn_mfma_f32_16x16x32_f16(aQi, bKi, sII, 0, 0, 0);
        sRI = __builtin_amdgcn_mfma_f32_16x16x32_f16(aQr, bKi, sRI, 0, 0, 0);
        sIR = __builtin_amdgcn_mfma_f32_16x16x32_f16(aQi, bKr, sIR, 0, 0, 0);
      }

      // ---- online softmax (row = q*4+r, col = lc) ----
#pragma unroll
      for (int r = 0; r < 4; ++r) {
        // real component
        {
          float v = sRR[r] - sII[r];
          float mx = v;
          mx = fmaxf(mx, __shfl_xor(mx, 1));
          mx = fmaxf(mx, __shfl_xor(mx, 2));
          mx = fmaxf(mx, __shfl_xor(mx, 4));
          mx = fmaxf(mx, __shfl_xor(mx, 8));
          float mn = fmaxf(m_r[r], mx);
          float f = __expf(m_r[r] - mn);
          float u = __expf(v - mn);
          float su = u;
          su += __shfl_xor(su, 1);
          su += __shfl_xor(su, 2);
          su += __shfl_xor(su, 4);
          su += __shfl_xor(su, 8);
          l_r[r] = l_r[r] * f + su;
          m_r[r] = mn; fac_r[r] = f;
          sP[w * 640 + (q * 4 + r) * 20 + lc] = (_Float16)u;
        }
        // imag component
        {
          float v = sRI[r] + sIR[r];
          float mx = v;
          mx = fmaxf(mx, __shfl_xor(mx, 1));
          mx = fmaxf(mx, __shfl_xor(mx, 2));
          mx = fmaxf(mx, __shfl_xor(mx, 4));
          mx = fmaxf(mx, __shfl_xor(mx, 8));
          float mn = fmaxf(m_i[r], mx);
          float f = __expf(m_i[r] - mn);
          float u = __expf(v - mn);
          float su = u;
          su += __shfl_xor(su, 1);
          su += __shfl_xor(su, 2);
          su += __shfl_xor(su, 4);
          su += __shfl_xor(su, 8);
          l_i[r] = l_i[r] * f + su;
          m_i[r] = mn; fac_i[r] = f;
          sP[w * 640 + 320 + (q * 4 + r) * 20 + lc] = (_Float16)u;
        }
      }

      // ---- PV over this wave's e-slice (per-wave P buffer; wave-internal
      // LDS RAW ordered by lgkmcnt) ----
      f16x4 aPr = *(const f16x4*)(sP + w * 640 + lc * 20 + q * 4);
      f16x4 aPi = *(const f16x4*)(sP + w * 640 + 320 + lc * 20 + q * 4);
#pragma unroll
      for (int ti = 0; ti < 5; ++ti) {
        if (ti < nt) {
          int et = t0 + ti;
          f16x4 bVr = *(const f16x4*)(sVT + (et * 16 + lc) * 20 + q * 4);
          f16x4 bVi = *(const f16x4*)(sVT + 272 * 20 + (et * 16 + lc) * 20 + q * 4);
#pragma unroll
          for (int r = 0; r < 4; ++r) {
            accRR[ti][r] *= fac_r[r]; accRI[ti][r] *= fac_r[r];
            accIR[ti][r] *= fac_i[r]; accII[ti][r] *= fac_i[r];
          }
          accRR[ti] = __builtin_amdgcn_mfma_f32_16x16x16f16(aPr, bVr, accRR[ti], 0, 0, 0);
          accRI[ti] = __builtin_amdgcn_mfma_f32_16x16x16f16(aPr, bVi, accRI[ti], 0, 0, 0);
          accIR[ti] = __builtin_amdgcn_mfma_f32_16x16x16f16(aPi, bVr, accIR[ti], 0, 0, 0);
          accII[ti] = __builtin_amdgcn_mfma_f32_16x16x16f16(aPi, bVi, accII[ti], 0, 0, 0);
        }
      }
    }

    // ---- finalize pass: combine with per-row denominators ----
#pragma unroll
    for (int r = 0; r < 4; ++r) {
      float ir = 1.0f / l_r[r];
      float ii = 1.0f / l_i[r];
#pragma unroll
      for (int ti = 0; ti < 5; ++ti) {
        if (ti < nt) {
          outR[ti][r] += accRR[ti][r] * ir - accII[ti][r] * ii;
          outI[ti][r] += accRI[ti][r] * ir + accIR[ti][r] * ii;
        }
      }
    }
  }

  // ---- store OX rows (ld 520): [re(257) | im(257)] ----
  {
    float* obase = OX + (size_t)(b * 512 + rt * 16) * LD_XF;
#pragma unroll
    for (int ti = 0; ti < 5; ++ti) {
      if (ti < nt) {
        int e = (t0 + ti) * 16 + lc;
        if (e < 257) {
#pragma unroll
          for (int r = 0; r < 4; ++r) {
            float* dst = obase + (size_t)(q * 4 + r) * LD_XF;
            dst[e] = outR[ti][r];
            dst[257 + e] = outI[ti][r];
          }
        }
      }
    }
  }
}

// ---------------- launch ----------------

extern "C" void kernel_launch(void* const* d_in, const int* in_sizes, int n_in,
                              void* d_out, int out_size, void* d_ws, size_t ws_size,
                              hipStream_t stream) {
  const float* x   = (const float*)d_in[0];
  const float* l1r = (const float*)d_in[1];
  const float* l1i = (const float*)d_in[2];
  const float* h1r = (const float*)d_in[3];
  const float* h1i = (const float*)d_in[4];
  const float* lbr = (const float*)d_in[5];
  const float* lbi = (const float*)d_in[6];
  const float* hbr = (const float*)d_in[7];
  const float* hbi = (const float*)d_in[8];
  float* out = (float*)d_out;

  float* ws = (float*)d_ws;
  size_t off = 0;
  float* xf = ws + off; off += (size_t)32768 * LD_XF;   // also reused as OX
  float* LH = ws + off; off += (size_t)32768 * LD_LH;
  float* Bf = ws + off; off += (size_t)512 * LD_BF;
  float* Bp = ws + off; off += (size_t)514 * 1028;
  float* iD = ws + off; off += (size_t)514 * 512;

  build_dft_kernel<<<(512 * 514 + 255) / 256, 256, 0, stream>>>(Bf);
  build_proj_kernel<<<(514 * 1028 + 255) / 256, 256, 0, stream>>>(l1r, l1i, h1r, h1i, Bp);
  build_idft_kernel<<<(514 * 512 + 255) / 256, 256, 0, stream>>>(iD);

  // rfft: xf = x @ Bf
  gemm_f32<<<dim3((514 + 63) / 64, 32768 / 64), 256, 0, stream>>>(
      x, 512, Bf, LD_BF, xf, LD_XF, 32768, 514, 512);
  // projections: LH = xf @ Bp
  gemm_f32<<<dim3((1028 + 63) / 64, 32768 / 64), 256, 0, stream>>>(
      xf, LD_XF, Bp, 1028, LH, LD_LH, 32768, 1028, 514);
  bias_relu_kernel<<<32768, 256, 0, stream>>>(LH, lbr, lbi, hbr, hbi);
  // attention -> OX (= xf buffer)
  attn_mfma<<<dim3(32, 64), 256, 0, stream>>>(LH, xf);
  // irfft: out = OX @ iD
  gemm_f32<<<dim3(512 / 64, 32768 / 64), 256, 0, stream>>>(
      xf, LD_XF, iD, 512, out, 512, 32768, 512, 514);
}

// Round 3
// 2135.109 us; speedup vs baseline: 2.9846x; 1.6376x over previous
//
#include <hip/hip_runtime.h>
#include <math.h>

// B=64, C=512, S=512, E=257, LK=128, HK=129.
// high_x is dead code in the reference: only low_x = attn(low,low,low)+attn(low,high,low).
//
// Pipeline:
//  1. build Bf (512x514): DFT matrix (cos | -sin) / sqrt(512)
//  2. build Bp (514x1028): complex projection blocks
//  3. build iD (514x512): inverse rfft matrix
//  4. gemm_f32: xf = x @ Bf                     (rows [Xr|Xi], ld 520)
//  5. gemm_proj: bias+relu+scale, writes f16 LHf16 [s*lowr|s*lowi|s*highr|s*highi]
//     (264-pad sub-blocks) and VTg (V transposed [b][comp][e][j]), s = sqrt(1/sqrt(257))
//  6. cooperative MFMA f16 flash attention (no staging, direct-global frags) -> OX
//  7. gemm_f32: out = OX @ iD

#define LD_XF 520
#define LD_BF 516
#define LD16 1056   // f16 row: 4 sub-blocks of 264

typedef __attribute__((ext_vector_type(4))) _Float16 f16x4;
typedef __attribute__((ext_vector_type(8))) _Float16 f16x8;
typedef __attribute__((ext_vector_type(4))) float f32x4;

#define S_FOLD 0.24975653f    // sqrt(1/sqrt(257))
#define INV_S  4.0039005f     // 1/S_FOLD

// ---------------- prep kernels ----------------

__global__ __launch_bounds__(256) void build_dft_kernel(float* __restrict__ Bf) {
  int idx = blockIdx.x * 256 + threadIdx.x;
  const int total = 512 * 514;
  if (idx >= total) return;
  int n = idx / 514;
  int col = idx - n * 514;
  int k = (col < 257) ? col : col - 257;
  int m = (n * k) & 511;
  float ang = (float)m * 0.0122718463030851f;   // 2*pi/512
  const float sc = 0.0441941738241592f;         // 1/sqrt(512)
  float v = (col < 257) ? cosf(ang) * sc : -sinf(ang) * sc;
  Bf[(size_t)n * LD_BF + col] = v;
}

__global__ __launch_bounds__(256) void build_proj_kernel(
    const float* __restrict__ l1r, const float* __restrict__ l1i,
    const float* __restrict__ h1r, const float* __restrict__ h1i,
    float* __restrict__ Bp) {
  int idx = blockIdx.x * 256 + threadIdx.x;
  const int total = 514 * 1028;
  if (idx >= total) return;
  int j = idx / 1028;
  int col = idx - j * 1028;
  float v = 0.0f;
  if (j < 128) {
    int k = j;
    if (col < 257) v = l1r[k * 257 + col];
    else if (col < 514) v = l1i[k * 257 + (col - 257)];
  } else if (j < 257) {
    int k = j - 128;
    if (col >= 514 && col < 771) v = h1r[k * 257 + (col - 514)];
    else if (col >= 771) v = h1i[k * 257 + (col - 771)];
  } else if (j < 385) {
    int k = j - 257;
    if (col < 257) v = -l1i[k * 257 + col];
    else if (col < 514) v = l1r[k * 257 + (col - 257)];
  } else {
    int k = j - 385;
    if (col >= 514 && col < 771) v = -h1i[k * 257 + (col - 514)];
    else if (col >= 771) v = h1r[k * 257 + (col - 771)];
  }
  Bp[(size_t)j * 1028 + col] = v;
}

__global__ __launch_bounds__(256) void build_idft_kernel(float* __restrict__ iD) {
  int idx = blockIdx.x * 256 + threadIdx.x;
  const int total = 514 * 512;
  if (idx >= total) return;
  int kc = idx / 512;
  int n = idx - kc * 512;
  int k = (kc < 257) ? kc : kc - 257;
  int m = (n * k) & 511;
  float ang = (float)m * 0.0122718463030851f;
  const float sc = 0.0441941738241592f;
  float c = (k == 0 || k == 256) ? 1.0f : 2.0f;
  float v = (kc < 257) ? c * sc * cosf(ang) : -c * sc * sinf(ang);
  iD[(size_t)kc * 512 + n] = v;
}

// ---------------- generic fp32 tiled GEMM: C = A(MxK) @ B(KxN) ----------------

__global__ __launch_bounds__(256) void gemm_f32(
    const float* __restrict__ A, int lda,
    const float* __restrict__ Bm, int ldb,
    float* __restrict__ Cm, int ldc,
    int M, int N, int K) {
  __shared__ __align__(16) float As[16][72];
  __shared__ __align__(16) float Bs[16][72];
  int t = threadIdx.x;
  int tx = t & 15;
  int ty = t >> 4;
  int row0 = blockIdx.y * 64;
  int col0 = blockIdx.x * 64;
  float acc[4][4] = {{0.f}};

  for (int k0 = 0; k0 < K; k0 += 16) {
    {
      int m = t >> 2;
      int k4 = (t & 3) * 4;
      const float* src = A + (size_t)(row0 + m) * lda + k0 + k4;
      float vx = 0.f, vy = 0.f, vz = 0.f, vw = 0.f;
      if (k0 + k4 + 3 < K) {
        float4 v = *(const float4*)src;
        vx = v.x; vy = v.y; vz = v.z; vw = v.w;
      } else {
        if (k0 + k4 + 0 < K) vx = src[0];
        if (k0 + k4 + 1 < K) vy = src[1];
        if (k0 + k4 + 2 < K) vz = src[2];
        if (k0 + k4 + 3 < K) vw = src[3];
      }
      As[k4 + 0][m] = vx; As[k4 + 1][m] = vy;
      As[k4 + 2][m] = vz; As[k4 + 3][m] = vw;
    }
    {
      int kb = t >> 4;
      int n4 = (t & 15) * 4;
      float4 v = {0.f, 0.f, 0.f, 0.f};
      if (k0 + kb < K) {
        const float* src = Bm + (size_t)(k0 + kb) * ldb + col0 + n4;
        if (col0 + n4 + 3 < N) {
          v = *(const float4*)src;
        } else {
          if (col0 + n4 + 0 < N) v.x = src[0];
          if (col0 + n4 + 1 < N) v.y = src[1];
          if (col0 + n4 + 2 < N) v.z = src[2];
          if (col0 + n4 + 3 < N) v.w = src[3];
        }
      }
      *(float4*)&Bs[kb][n4] = v;
    }
    __syncthreads();
#pragma unroll
    for (int kk = 0; kk < 16; ++kk) {
      float4 av = *(const float4*)&As[kk][ty * 4];
      float4 bv = *(const float4*)&Bs[kk][tx * 4];
      float a0 = av.x, a1 = av.y, a2 = av.z, a3 = av.w;
      float b0 = bv.x, b1 = bv.y, b2 = bv.z, b3 = bv.w;
      acc[0][0] += a0 * b0; acc[0][1] += a0 * b1; acc[0][2] += a0 * b2; acc[0][3] += a0 * b3;
      acc[1][0] += a1 * b0; acc[1][1] += a1 * b1; acc[1][2] += a1 * b2; acc[1][3] += a1 * b3;
      acc[2][0] += a2 * b0; acc[2][1] += a2 * b1; acc[2][2] += a2 * b2; acc[2][3] += a2 * b3;
      acc[3][0] += a3 * b0; acc[3][1] += a3 * b1; acc[3][2] += a3 * b2; acc[3][3] += a3 * b3;
    }
    __syncthreads();
  }
#pragma unroll
  for (int i = 0; i < 4; ++i) {
    int r = row0 + ty * 4 + i;
#pragma unroll
    for (int j = 0; j < 4; ++j) {
      int c = col0 + tx * 4 + j;
      if (c < N) Cm[(size_t)r * ldc + c] = acc[i][j];
    }
  }
}

// ---------------- projection GEMM with fused bias+relu+scale+f16 pack ----------------
// A = xf (32768 x 514, ld 520), B = Bp (514 x 1028).
// Epilogue: v = relu(acc + bias[col]) * S_FOLD
//   -> LHf16[row][sub*264 + e]           (sub = col/257, e = col%257)
//   -> VTg[(b*2+sub)*272*512 + e*512 + j] for sub<2  (b=row/512, j=row%512)

__global__ __launch_bounds__(256) void gemm_proj(
    const float* __restrict__ A,
    const float* __restrict__ Bm,
    const float* __restrict__ lbr, const float* __restrict__ lbi,
    const float* __restrict__ hbr, const float* __restrict__ hbi,
    _Float16* __restrict__ LHf, _Float16* __restrict__ VTg) {
  const int lda = LD_XF, ldb = 1028, N = 1028, K = 514;
  __shared__ __align__(16) float As[16][72];
  __shared__ __align__(16) float Bs[16][72];
  int t = threadIdx.x;
  int tx = t & 15;
  int ty = t >> 4;
  int row0 = blockIdx.y * 64;
  int col0 = blockIdx.x * 64;
  float acc[4][4] = {{0.f}};

  for (int k0 = 0; k0 < K; k0 += 16) {
    {
      int m = t >> 2;
      int k4 = (t & 3) * 4;
      const float* src = A + (size_t)(row0 + m) * lda + k0 + k4;
      float vx = 0.f, vy = 0.f, vz = 0.f, vw = 0.f;
      if (k0 + k4 + 3 < K) {
        float4 v = *(const float4*)src;
        vx = v.x; vy = v.y; vz = v.z; vw = v.w;
      } else {
        if (k0 + k4 + 0 < K) vx = src[0];
        if (k0 + k4 + 1 < K) vy = src[1];
      }
      As[k4 + 0][m] = vx; As[k4 + 1][m] = vy;
      As[k4 + 2][m] = vz; As[k4 + 3][m] = vw;
    }
    {
      int kb = t >> 4;
      int n4 = (t & 15) * 4;
      float4 v = {0.f, 0.f, 0.f, 0.f};
      if (k0 + kb < K) {
        const float* src = Bm + (size_t)(k0 + kb) * ldb + col0 + n4;
        if (col0 + n4 + 3 < N) {
          v = *(const float4*)src;
        } else {
          if (col0 + n4 + 0 < N) v.x = src[0];
          if (col0 + n4 + 1 < N) v.y = src[1];
          if (col0 + n4 + 2 < N) v.z = src[2];
          if (col0 + n4 + 3 < N) v.w = src[3];
        }
      }
      *(float4*)&Bs[kb][n4] = v;
    }
    __syncthreads();
#pragma unroll
    for (int kk = 0; kk < 16; ++kk) {
      float4 av = *(const float4*)&As[kk][ty * 4];
      float4 bv = *(const float4*)&Bs[kk][tx * 4];
      float a0 = av.x, a1 = av.y, a2 = av.z, a3 = av.w;
      float b0 = bv.x, b1 = bv.y, b2 = bv.z, b3 = bv.w;
      acc[0][0] += a0 * b0; acc[0][1] += a0 * b1; acc[0][2] += a0 * b2; acc[0][3] += a0 * b3;
      acc[1][0] += a1 * b0; acc[1][1] += a1 * b1; acc[1][2] += a1 * b2; acc[1][3] += a1 * b3;
      acc[2][0] += a2 * b0; acc[2][1] += a2 * b1; acc[2][2] += a2 * b2; acc[2][3] += a2 * b3;
      acc[3][0] += a3 * b0; acc[3][1] += a3 * b1; acc[3][2] += a3 * b2; acc[3][3] += a3 * b3;
    }
    __syncthreads();
  }
#pragma unroll
  for (int i = 0; i < 4; ++i) {
    int r = row0 + ty * 4 + i;
    int bb = r >> 9;
    int jj = r & 511;
#pragma unroll
    for (int j = 0; j < 4; ++j) {
      int c = col0 + tx * 4 + j;
      if (c < N) {
        int sub = (c >= 771) ? 3 : (c >= 514) ? 2 : (c >= 257) ? 1 : 0;
        int e = c - sub * 257;
        float bv = (sub == 0) ? lbr[e] : (sub == 1) ? lbi[e] : (sub == 2) ? hbr[e] : hbi[e];
        float v = fmaxf(acc[i][j] + bv, 0.f) * S_FOLD;
        LHf[(size_t)r * LD16 + sub * 264 + e] = (_Float16)v;
        if (sub < 2)
          VTg[(((size_t)bb * 2 + sub) * 272 + e) * 512 + jj] = (_Float16)v;
      }
    }
  }
}

// ---------------- cooperative MFMA f16 flash attention ----------------
// Block = (batch b, 16 Q-rows), 4 waves. Chunk = 64 K-cols; wave w owns j-slice
// [j0+w*16, j0+w*16+16). Scores via mfma 16x16x32 (k = e, 9 chunks, direct-global
// B frags; Q frags resident in regs). Cross-wave softmax via tiny LDS stats; P
// shared via LDS (A-layout); PV via mfma 16x16x16 over k=64, V frags direct from
// pre-transposed global VTg. 2 barriers per chunk, 32 total. Values pre-scaled by
// S_FOLD so scores carry 1/sqrt(257); output denominator multiplied by INV_S.

__global__ __launch_bounds__(256, 2) void attn_mfma2(
    const _Float16* __restrict__ LHf, const _Float16* __restrict__ VTg,
    float* __restrict__ OX) {
  int bid = blockIdx.x;
  int xcd = bid & 7;
  int ix = bid >> 3;            // 0..255 within XCD
  int rt = ix & 31;
  int b = xcd + 8 * (ix >> 5);  // keep one batch's blocks on one XCD (L2 locality)
  int t = threadIdx.x;
  int w = t >> 6;
  int L = t & 63;
  int q = L >> 4;
  int lc = L & 15;

  __shared__ _Float16 sP[2][16][76];
  __shared__ float sMax[2][16][4];
  __shared__ float sSum[2][16][4];

  const f16x8 zero8 = {(_Float16)0, (_Float16)0, (_Float16)0, (_Float16)0,
                       (_Float16)0, (_Float16)0, (_Float16)0, (_Float16)0};

  // resident Q fragments: A-frag lane m=lc, k = ec*32 + q*8 + i
  const _Float16* qbase = LHf + (size_t)(b * 512 + rt * 16 + lc) * LD16;
  f16x8 Qf[2][9];
#pragma unroll
  for (int comp = 0; comp < 2; ++comp)
#pragma unroll
    for (int ec = 0; ec < 9; ++ec)
      Qf[comp][ec] = (ec == 8 && q != 0)
                         ? zero8
                         : *(const f16x8*)(qbase + comp * 264 + ec * 32 + q * 8);

  const int t0s[4] = {0, 5, 9, 13};
  const int nts[4] = {5, 4, 4, 4};
  int t0 = t0s[w], nt = nts[w];

  f32x4 outR[5], outI[5];
#pragma unroll
  for (int i = 0; i < 5; ++i) {
    outR[i] = f32x4{0.f, 0.f, 0.f, 0.f};
    outI[i] = f32x4{0.f, 0.f, 0.f, 0.f};
  }

  for (int pass = 0; pass < 2; ++pass) {
    int koff = pass * 528;  // 0: low (r/i at 0/264); 1: high (528/792)
    f32x4 accRR[5], accRI[5], accIR[5], accII[5];
    float m_r[4], l_r[4], m_i[4], l_i[4];
#pragma unroll
    for (int i = 0; i < 5; ++i) {
      accRR[i] = f32x4{0.f, 0.f, 0.f, 0.f};
      accRI[i] = f32x4{0.f, 0.f, 0.f, 0.f};
      accIR[i] = f32x4{0.f, 0.f, 0.f, 0.f};
      accII[i] = f32x4{0.f, 0.f, 0.f, 0.f};
    }
#pragma unroll
    for (int r = 0; r < 4; ++r) {
      m_r[r] = -3.0e38f; l_r[r] = 0.f;
      m_i[r] = -3.0e38f; l_i[r] = 0.f;
    }

    for (int jt = 0; jt < 8; ++jt) {
      int j0 = jt * 64;
      // ---- scores for this wave's 16-j slice ----
      const _Float16* kbase =
          LHf + (size_t)(b * 512 + j0 + w * 16 + lc) * LD16 + koff;
      f32x4 sRR = f32x4{0.f, 0.f, 0.f, 0.f};
      f32x4 sII = f32x4{0.f, 0.f, 0.f, 0.f};
      f32x4 sRI = f32x4{0.f, 0.f, 0.f, 0.f};
      f32x4 sIR = f32x4{0.f, 0.f, 0.f, 0.f};
#pragma unroll
      for (int ec = 0; ec < 9; ++ec) {
        f16x8 bKr, bKi;
        if (ec == 8 && q != 0) {
          bKr = zero8; bKi = zero8;
        } else {
          bKr = *(const f16x8*)(kbase + ec * 32 + q * 8);
          bKi = *(const f16x8*)(kbase + 264 + ec * 32 + q * 8);
        }
        sRR = __builtin_amdgcn_mfma_f32_16x16x32_f16(Qf[0][ec], bKr, sRR, 0, 0, 0);
        sII = __builtin_amdgcn_mfma_f32_16x16x32_f16(Qf[1][ec], bKi, sII, 0, 0, 0);
        sRI = __builtin_amdgcn_mfma_f32_16x16x32_f16(Qf[0][ec], bKi, sRI, 0, 0, 0);
        sIR = __builtin_amdgcn_mfma_f32_16x16x32_f16(Qf[1][ec], bKr, sIR, 0, 0, 0);
      }

      float vr[4], vi[4], mxr[4], mxi[4];
#pragma unroll
      for (int r = 0; r < 4; ++r) {
        vr[r] = sRR[r] - sII[r];
        vi[r] = sRI[r] + sIR[r];
        float m0 = vr[r];
        m0 = fmaxf(m0, __shfl_xor(m0, 1));
        m0 = fmaxf(m0, __shfl_xor(m0, 2));
        m0 = fmaxf(m0, __shfl_xor(m0, 4));
        m0 = fmaxf(m0, __shfl_xor(m0, 8));
        mxr[r] = m0;
        float m1 = vi[r];
        m1 = fmaxf(m1, __shfl_xor(m1, 1));
        m1 = fmaxf(m1, __shfl_xor(m1, 2));
        m1 = fmaxf(m1, __shfl_xor(m1, 4));
        m1 = fmaxf(m1, __shfl_xor(m1, 8));
        mxi[r] = m1;
        if (lc == 0) {
          sMax[0][q * 4 + r][w] = m0;
          sMax[1][q * 4 + r][w] = m1;
        }
      }
      __syncthreads();  // publish per-wave maxes

      float fac_r[4], fac_i[4];
#pragma unroll
      for (int r = 0; r < 4; ++r) {
        int row = q * 4 + r;
        {
          f32x4 g = *(const f32x4*)&sMax[0][row][0];
          float mt = fmaxf(fmaxf(g[0], g[1]), fmaxf(g[2], g[3]));
          float mn = fmaxf(m_r[r], mt);
          fac_r[r] = __expf(m_r[r] - mn);
          m_r[r] = mn;
          float u = __expf(vr[r] - mn);
          sP[0][row][w * 16 + lc] = (_Float16)u;
          float su = u;
          su += __shfl_xor(su, 1);
          su += __shfl_xor(su, 2);
          su += __shfl_xor(su, 4);
          su += __shfl_xor(su, 8);
          if (lc == 0) sSum[0][row][w] = su;
        }
        {
          f32x4 g = *(const f32x4*)&sMax[1][row][0];
          float mt = fmaxf(fmaxf(g[0], g[1]), fmaxf(g[2], g[3]));
          float mn = fmaxf(m_i[r], mt);
          fac_i[r] = __expf(m_i[r] - mn);
          m_i[r] = mn;
          float u = __expf(vi[r] - mn);
          sP[1][row][w * 16 + lc] = (_Float16)u;
          float su = u;
          su += __shfl_xor(su, 1);
          su += __shfl_xor(su, 2);
          su += __shfl_xor(su, 4);
          su += __shfl_xor(su, 8);
          if (lc == 0) sSum[1][row][w] = su;
        }
      }
      __syncthreads();  // publish P tiles + per-wave sums

#pragma unroll
      for (int r = 0; r < 4; ++r) {
        int row = q * 4 + r;
        f32x4 s0 = *(const f32x4*)&sSum[0][row][0];
        l_r[r] = l_r[r] * fac_r[r] + (s0[0] + s0[1] + s0[2] + s0[3]);
        f32x4 s1 = *(const f32x4*)&sSum[1][row][0];
        l_i[r] = l_i[r] * fac_i[r] + (s1[0] + s1[1] + s1[2] + s1[3]);
      }

      // ---- PV: A-frags from sP (k=64), B-frags direct from VTg ----
      f16x4 aPr[4], aPi[4];
#pragma unroll
      for (int ks = 0; ks < 4; ++ks) {
        aPr[ks] = *(const f16x4*)&sP[0][lc][ks * 16 + q * 4];
        aPi[ks] = *(const f16x4*)&sP[1][lc][ks * 16 + q * 4];
      }
#pragma unroll
      for (int ti = 0; ti < 5; ++ti) {
        if (ti < nt) {
          int e = (t0 + ti) * 16 + lc;
          const _Float16* vbr = VTg + (((size_t)b * 2 + 0) * 272 + e) * 512 + j0;
          const _Float16* vbi = VTg + (((size_t)b * 2 + 1) * 272 + e) * 512 + j0;
#pragma unroll
          for (int r = 0; r < 4; ++r) {
            accRR[ti][r] *= fac_r[r]; accRI[ti][r] *= fac_r[r];
            accIR[ti][r] *= fac_i[r]; accII[ti][r] *= fac_i[r];
          }
#pragma unroll
          for (int ks = 0; ks < 4; ++ks) {
            f16x4 bVr = *(const f16x4*)(vbr + ks * 16 + q * 4);
            f16x4 bVi = *(const f16x4*)(vbi + ks * 16 + q * 4);
            accRR[ti] = __builtin_amdgcn_mfma_f32_16x16x16f16(aPr[ks], bVr, accRR[ti], 0, 0, 0);
            accRI[ti] = __builtin_amdgcn_mfma_f32_16x16x16f16(aPr[ks], bVi, accRI[ti], 0, 0, 0);
            accIR[ti] = __builtin_amdgcn_mfma_f32_16x16x16f16(aPi[ks], bVr, accIR[ti], 0, 0, 0);
            accII[ti] = __builtin_amdgcn_mfma_f32_16x16x16f16(aPi[ks], bVi, accII[ti], 0, 0, 0);
          }
        }
      }
    }

    // ---- finalize pass (INV_S compensates V pre-scaling) ----
#pragma unroll
    for (int r = 0; r < 4; ++r) {
      float ir = INV_S / l_r[r];
      float ii = INV_S / l_i[r];
#pragma unroll
      for (int ti = 0; ti < 5; ++ti) {
        if (ti < nt) {
          outR[ti][r] += accRR[ti][r] * ir - accII[ti][r] * ii;
          outI[ti][r] += accRI[ti][r] * ir + accIR[ti][r] * ii;
        }
      }
    }
  }

  // ---- store OX rows (ld 520): [re(257) | im(257)] ----
  float* obase = OX + (size_t)(b * 512 + rt * 16) * LD_XF;
#pragma unroll
  for (int ti = 0; ti < 5; ++ti) {
    if (ti < nt) {
      int e = (t0 + ti) * 16 + lc;
      if (e < 257) {
#pragma unroll
        for (int r = 0; r < 4; ++r) {
          float* dst = obase + (size_t)(q * 4 + r) * LD_XF;
          dst[e] = outR[ti][r];
          dst[257 + e] = outI[ti][r];
        }
      }
    }
  }
}

// ---------------- launch ----------------

extern "C" void kernel_launch(void* const* d_in, const int* in_sizes, int n_in,
                              void* d_out, int out_size, void* d_ws, size_t ws_size,
                              hipStream_t stream) {
  const float* x   = (const float*)d_in[0];
  const float* l1r = (const float*)d_in[1];
  const float* l1i = (const float*)d_in[2];
  const float* h1r = (const float*)d_in[3];
  const float* h1i = (const float*)d_in[4];
  const float* lbr = (const float*)d_in[5];
  const float* lbi = (const float*)d_in[6];
  const float* hbr = (const float*)d_in[7];
  const float* hbi = (const float*)d_in[8];
  float* out = (float*)d_out;

  float* ws = (float*)d_ws;
  size_t off = 0;
  float* xf = ws + off; off += (size_t)32768 * LD_XF;   // reused as OX
  float* Bf = ws + off; off += (size_t)512 * LD_BF;
  float* Bp = ws + off; off += (size_t)514 * 1028;
  float* iD = ws + off; off += (size_t)514 * 512;
  _Float16* LHf = (_Float16*)(ws + off); off += (size_t)32768 * LD16 / 2;
  _Float16* VTg = (_Float16*)(ws + off); off += (size_t)64 * 2 * 272 * 512 / 2;
  // total ~177.3 MB

  // zero f16 buffers (pads must be 0 for MFMA frags)
  hipMemsetAsync(LHf, 0, (size_t)32768 * LD16 * 2, stream);
  hipMemsetAsync(VTg, 0, (size_t)64 * 2 * 272 * 512 * 2, stream);

  build_dft_kernel<<<(512 * 514 + 255) / 256, 256, 0, stream>>>(Bf);
  build_proj_kernel<<<(514 * 1028 + 255) / 256, 256, 0, stream>>>(l1r, l1i, h1r, h1i, Bp);
  build_idft_kernel<<<(514 * 512 + 255) / 256, 256, 0, stream>>>(iD);

  // rfft: xf = x @ Bf
  gemm_f32<<<dim3((514 + 63) / 64, 32768 / 64), 256, 0, stream>>>(
      x, 512, Bf, LD_BF, xf, LD_XF, 32768, 514, 512);
  // projections + bias + relu + f16 pack (LHf, VTg)
  gemm_proj<<<dim3((1028 + 63) / 64, 32768 / 64), 256, 0, stream>>>(
      xf, Bp, lbr, lbi, hbr, hbi, LHf, VTg);
  // attention -> OX (= xf buffer)
  attn_mfma2<<<2048, 256, 0, stream>>>(LHf, VTg, xf);
  // irfft: out = OX @ iD
  gemm_f32<<<dim3(512 / 64, 32768 / 64), 256, 0, stream>>>(
      xf, LD_XF, iD, 512, out, 512, 32768, 512, 514);
}

// Round 4
// 1137.043 us; speedup vs baseline: 5.6045x; 1.8778x over previous
//
#include <hip/hip_runtime.h>
#include <math.h>

// B=64, C=512, S=512, E=257, LK=128, HK=129.
// high_x is dead code in the reference: only low_x = attn(low,low,low)+attn(low,high,low).
//
// Pipeline (all heavy math on MFMA f16):
//  1. build_W: Wt[c][n] f16 = combined rfft+projection weight (512 -> 1028), B-transposed
//  2. build_idt: iDt[n][k] f16 = irfft matrix matching OXh row layout [re264|im264]
//  3. gemm_main (MFMA f16): LHf = relu(x @ W + bias) * S_FOLD, f16 rows [lr|li|hr|hi] (264 pad)
//  4. repack_K: LHf -> Kpack in exact MFMA B-frag order (coalesced attention loads)
//  5. repack_V: LHf low -> Vpack (LDS transpose) in PV B-frag order
//  6. attn (MFMA f16 flash): frag loads fully coalesced; writes OXh f16 into LHf[.][528..1056)
//  7. gemm_irfft (MFMA f16): out = OXh @ iDt
//
// ws: LHf 69.2 MB + Kpack 75.5 MB + Vpack 35.7 MB + Wt 1.1 MB + iDt 0.6 MB ~= 182 MB.

#define LD16 1056   // halves per LHf row: [lr 264 | li 264 | hr 264 | hi 264]
#define OXOFF 528   // OXh f16 output written into LHf[row][528..1056): [re 264 | im 264]

typedef __attribute__((ext_vector_type(4))) _Float16 f16x4;
typedef __attribute__((ext_vector_type(8))) _Float16 f16x8;
typedef __attribute__((ext_vector_type(4))) float f32x4;

#define S_FOLD 0.24975653f    // sqrt(1/sqrt(257))
#define INV_S  4.0039005f     // 1/S_FOLD
#define SC512  0.0441941738241592f   // 1/sqrt(512)

// ---------------- build combined rfft+projection weight, B-transposed ----------------
// Wt[c][n], c in [0,1088), n in [0,512). c>=1028 -> 0.
// c<257: low_r; 257..513: low_i; 514..770: high_r; 771..1027: high_i.

__global__ __launch_bounds__(256) void build_W(
    const float* __restrict__ l1r, const float* __restrict__ l1i,
    const float* __restrict__ h1r, const float* __restrict__ h1i,
    _Float16* __restrict__ Wt) {
  int c = blockIdx.x;
  int t = threadIdx.x;
  if (c >= 1028) {
    for (int n = t; n < 512; n += 256) Wt[(size_t)c * 512 + n] = (_Float16)0.0f;
    return;
  }
  __shared__ float Tc[512], Ts[512];
  __shared__ float wr[132], wi[132];
  for (int i = t; i < 512; i += 256) {
    float ang = (float)i * 0.0122718463030851f;  // 2*pi/512
    Tc[i] = cosf(ang);
    Ts[i] = sinf(ang);
  }
  int sub = (c >= 771) ? 3 : (c >= 514) ? 2 : (c >= 257) ? 1 : 0;
  int e = c - sub * 257;
  int Kn = (sub < 2) ? 128 : 129;
  int kb = (sub < 2) ? 0 : 128;
  if (t < Kn) {
    if (sub < 2) { wr[t] = l1r[t * 257 + e]; wi[t] = l1i[t * 257 + e]; }
    else         { wr[t] = h1r[t * 257 + e]; wi[t] = h1i[t * 257 + e]; }
  }
  __syncthreads();
  bool imag_out = (sub & 1);
  for (int n = t; n < 512; n += 256) {
    float acc = 0.f;
    for (int k = 0; k < Kn; ++k) {
      int kk = kb + k;
      int m = (n * kk) & 511;
      float Fr = Tc[m] * SC512;
      float Fi = -Ts[m] * SC512;
      if (!imag_out) acc += Fr * wr[k] - Fi * wi[k];
      else           acc += Fr * wi[k] + Fi * wr[k];
    }
    Wt[(size_t)c * 512 + n] = (_Float16)acc;
  }
}

// ---------------- build irfft matrix, B-transposed, matching OXh layout ----------------
// iDt[n][k], n in [0,512), k in [0,544). k<264: e=k cos part; 264..527: e=k-264 sin part.

__global__ __launch_bounds__(256) void build_idt(_Float16* __restrict__ iDt) {
  int idx = blockIdx.x * 256 + threadIdx.x;
  const int total = 512 * 544;
  if (idx >= total) return;
  int n = idx / 544;
  int k = idx - n * 544;
  float val = 0.f;
  if (k < 264) {
    int e = k;
    if (e <= 256) {
      float ce = (e == 0 || e == 256) ? 1.f : 2.f;
      int m = (n * e) & 511;
      val = ce * SC512 * cosf((float)m * 0.0122718463030851f);
    }
  } else if (k < 528) {
    int e = k - 264;
    if (e <= 256) {
      float ce = (e == 0 || e == 256) ? 1.f : 2.f;
      int m = (n * e) & 511;
      val = -ce * SC512 * sinf((float)m * 0.0122718463030851f);
    }
  }
  iDt[(size_t)n * 544 + k] = (_Float16)val;
}

// ---------------- MFMA f16 GEMM: LHf = relu(x @ W + bias) * S_FOLD ----------------
// M=32768, N=1028 (17 tiles of 64), K=512. A fp32 converted in staging, B = Wt f16 [c][k].
// grid (17, 256), block 256 (4 waves); tile 128(M) x 64(N), BK=32.

__global__ __launch_bounds__(256) void gemm_main(
    const float* __restrict__ X, const _Float16* __restrict__ Wt,
    const float* __restrict__ lbr, const float* __restrict__ lbi,
    const float* __restrict__ hbr, const float* __restrict__ hbi,
    _Float16* __restrict__ LHf) {
  __shared__ __align__(16) char lds[33792];
  _Float16* As = (_Float16*)lds;              // [128][40]
  _Float16* Bs = (_Float16*)(lds + 10240);    // [64][40]
  float* CL = (float*)lds;                    // [128][66]

  int t = threadIdx.x;
  int w = t >> 6, L = t & 63, q = L >> 4, lc = L & 15;
  int row0 = blockIdx.y * 128;
  int n0 = blockIdx.x * 64;

  f32x4 acc[2][4];
#pragma unroll
  for (int i = 0; i < 2; ++i)
#pragma unroll
    for (int j = 0; j < 4; ++j) acc[i][j] = f32x4{0.f, 0.f, 0.f, 0.f};

  for (int k0 = 0; k0 < 512; k0 += 32) {
    // stage A (fp32 -> f16)
    {
      int m = t >> 1, half = t & 1;
      const float* src = X + (size_t)(row0 + m) * 512 + k0 + half * 16;
      float4 a0 = *(const float4*)(src + 0);
      float4 a1 = *(const float4*)(src + 4);
      float4 a2 = *(const float4*)(src + 8);
      float4 a3 = *(const float4*)(src + 12);
      f16x8 h0 = {(_Float16)a0.x, (_Float16)a0.y, (_Float16)a0.z, (_Float16)a0.w,
                  (_Float16)a1.x, (_Float16)a1.y, (_Float16)a1.z, (_Float16)a1.w};
      f16x8 h1 = {(_Float16)a2.x, (_Float16)a2.y, (_Float16)a2.z, (_Float16)a2.w,
                  (_Float16)a3.x, (_Float16)a3.y, (_Float16)a3.z, (_Float16)a3.w};
      *(f16x8*)(As + m * 40 + half * 16) = h0;
      *(f16x8*)(As + m * 40 + half * 16 + 8) = h1;
    }
    // stage B
    {
      int row = t >> 2, ch = t & 3;
      f16x8 bv = *(const f16x8*)(Wt + (size_t)(n0 + row) * 512 + k0 + ch * 8);
      *(f16x8*)(Bs + row * 40 + ch * 8) = bv;
    }
    __syncthreads();
#pragma unroll
    for (int sub = 0; sub < 2; ++sub) {
      f16x8 af = *(const f16x8*)(As + (w * 32 + sub * 16 + lc) * 40 + q * 8);
#pragma unroll
      for (int ns = 0; ns < 4; ++ns) {
        f16x8 bf = *(const f16x8*)(Bs + (ns * 16 + lc) * 40 + q * 8);
        acc[sub][ns] = __builtin_amdgcn_mfma_f32_16x16x32_f16(af, bf, acc[sub][ns], 0, 0, 0);
      }
    }
    __syncthreads();
  }

  // epilogue: reorder via LDS, then bias+relu+scale+f16 pack into LHf
#pragma unroll
  for (int sub = 0; sub < 2; ++sub)
#pragma unroll
    for (int ns = 0; ns < 4; ++ns)
#pragma unroll
      for (int r = 0; r < 4; ++r)
        CL[(w * 32 + sub * 16 + q * 4 + r) * 66 + ns * 16 + lc] = acc[sub][ns][r];
  __syncthreads();

#pragma unroll
  for (int rep = 0; rep < 8; ++rep) {
    int idx = rep * 256 + t;
    int row = idx >> 4;
    int c4 = idx & 15;
    f32x4 v = *(const f32x4*)(CL + row * 66 + c4 * 4);
    int rowg = row0 + row;
#pragma unroll
    for (int jj = 0; jj < 4; ++jj) {
      int c = n0 + c4 * 4 + jj;
      if (c < 1028) {
        int sub = (c >= 771) ? 3 : (c >= 514) ? 2 : (c >= 257) ? 1 : 0;
        int e = c - sub * 257;
        float bv = (sub == 0) ? lbr[e] : (sub == 1) ? lbi[e] : (sub == 2) ? hbr[e] : hbi[e];
        float val = fmaxf(v[jj] + bv, 0.f) * S_FOLD;
        LHf[(size_t)rowg * LD16 + sub * 264 + e] = (_Float16)val;
      }
    }
  }
}

// ---------------- repack K into MFMA B-frag-linear order ----------------
// Kpack chunk wc = (((b*2+pass)*2+comp)*32 + jt)*9 + ec ; chunk = [64 lanes][8 halves].
// Lane L: j = jt*16 + (L&15), e = ec*32 + (L>>4)*8 + i.

__global__ __launch_bounds__(256) void repack_K(
    const _Float16* __restrict__ LHf, _Float16* __restrict__ Kpack) {
  int t = threadIdx.x;
  int w = t >> 6, L = t & 63, q = L >> 4, lc = L & 15;
  int wc = blockIdx.x * 4 + w;
  int ec = wc % 9;
  int tmp = wc / 9;
  int jt = tmp & 31; tmp >>= 5;
  int comp = tmp & 1; tmp >>= 1;
  int pass = tmp & 1;
  int b = tmp >> 1;
  f16x8 v;
  if (ec == 8 && q > 0) {
    v = f16x8{(_Float16)0, (_Float16)0, (_Float16)0, (_Float16)0,
              (_Float16)0, (_Float16)0, (_Float16)0, (_Float16)0};
  } else {
    v = *(const f16x8*)(LHf + (size_t)(b * 512 + jt * 16 + lc) * LD16 +
                        pass * 528 + comp * 264 + ec * 32 + q * 8);
  }
  *(f16x8*)(Kpack + (size_t)wc * 512 + L * 8) = v;
}

// ---------------- repack V (low) into PV B-frag order via LDS transpose ----------------
// Vpack[b][comp][et(17)][ks(16)][64 lanes][8]; lane L: e = et*16+(L&15), j = ks*32+(L>>4)*8+i.

__global__ __launch_bounds__(256) void repack_V(
    const _Float16* __restrict__ LHf, _Float16* __restrict__ Vpack) {
  int bid = blockIdx.x;
  int et = bid % 17;
  int tmp = bid / 17;
  int comp = tmp & 1;
  int b = tmp >> 1;
  int t = threadIdx.x;
  __shared__ __align__(16) _Float16 tile[512 * 16];

  const f16x8 zero8 = {(_Float16)0, (_Float16)0, (_Float16)0, (_Float16)0,
                       (_Float16)0, (_Float16)0, (_Float16)0, (_Float16)0};
  for (int j = t; j < 512; j += 256) {
    const _Float16* src = LHf + (size_t)(b * 512 + j) * LD16 + comp * 264 + et * 16;
    f16x8 v0, v1;
    if (et < 16) {
      v0 = *(const f16x8*)(src);
      v1 = *(const f16x8*)(src + 8);
    } else {  // e = 256..271: only first 8 within sub-block (256 real, 257..263 zero)
      v0 = *(const f16x8*)(src);
      v1 = zero8;
    }
    *(f16x8*)(tile + j * 16) = v0;
    *(f16x8*)(tile + j * 16 + 8) = v1;
  }
  __syncthreads();

#pragma unroll
  for (int it = 0; it < 4; ++it) {
    int c2 = it * 256 + t;
    int ks = c2 >> 6;
    int L2 = c2 & 63;
    int q2 = L2 >> 4, lc2 = L2 & 15;
    f16x8 v;
#pragma unroll
    for (int i = 0; i < 8; ++i) v[i] = tile[(ks * 32 + q2 * 8 + i) * 16 + lc2];
    *(f16x8*)(Vpack + ((((size_t)(b * 2 + comp) * 17 + et) * 16 + ks) * 512) + L2 * 8) = v;
  }
}

// ---------------- MFMA f16 flash attention, fully-coalesced frag loads ----------------
// Block = (b, 16 Q-rows), 4 waves; chunk = 64 j; wave owns jtile = jt*4+w.
// Scores 16x16x32 from Kpack; P exchanged via LDS; PV 16x16x32 from Vpack.
// Output written f16 into LHf[row][528..1056) = OXh.

__global__ __launch_bounds__(256, 2) void attn_mfma3(
    const _Float16* __restrict__ LHf, const _Float16* __restrict__ Kpack,
    const _Float16* __restrict__ Vpack, _Float16* __restrict__ OXh) {
  int bid = blockIdx.x;
  int xcd = bid & 7;
  int ix = bid >> 3;
  int rt = ix & 31;
  int b = xcd + 8 * (ix >> 5);
  int t = threadIdx.x;
  int w = t >> 6, L = t & 63, q = L >> 4, lc = L & 15;

  __shared__ _Float16 sP[2][16][72];
  __shared__ float sMax[2][16][4];
  __shared__ float sSum[2][16][4];

  const f16x8 zero8 = {(_Float16)0, (_Float16)0, (_Float16)0, (_Float16)0,
                       (_Float16)0, (_Float16)0, (_Float16)0, (_Float16)0};

  // resident Q fragments (A-frag: m=lc, k=ec*32+q*8+i), gathered once
  const _Float16* qbase = LHf + (size_t)(b * 512 + rt * 16 + lc) * LD16;
  f16x8 Qf[2][9];
#pragma unroll
  for (int comp = 0; comp < 2; ++comp)
#pragma unroll
    for (int ec = 0; ec < 9; ++ec)
      Qf[comp][ec] = (ec == 8 && q != 0)
                         ? zero8
                         : *(const f16x8*)(qbase + comp * 264 + ec * 32 + q * 8);

  const int t0s[4] = {0, 5, 9, 13};
  const int nts[4] = {5, 4, 4, 4};
  int t0 = t0s[w], nt = nts[w];

  f32x4 outR[5], outI[5];
#pragma unroll
  for (int i = 0; i < 5; ++i) {
    outR[i] = f32x4{0.f, 0.f, 0.f, 0.f};
    outI[i] = f32x4{0.f, 0.f, 0.f, 0.f};
  }

  for (int pass = 0; pass < 2; ++pass) {
    f32x4 accRR[5], accRI[5], accIR[5], accII[5];
    float m_r[4], l_r[4], m_i[4], l_i[4];
#pragma unroll
    for (int i = 0; i < 5; ++i) {
      accRR[i] = f32x4{0.f, 0.f, 0.f, 0.f};
      accRI[i] = f32x4{0.f, 0.f, 0.f, 0.f};
      accIR[i] = f32x4{0.f, 0.f, 0.f, 0.f};
      accII[i] = f32x4{0.f, 0.f, 0.f, 0.f};
    }
#pragma unroll
    for (int r = 0; r < 4; ++r) {
      m_r[r] = -3.0e38f; l_r[r] = 0.f;
      m_i[r] = -3.0e38f; l_i[r] = 0.f;
    }

    for (int jt = 0; jt < 8; ++jt) {
      // ---- scores from Kpack (fully coalesced: base + L*16B) ----
      size_t kb0 = ((((size_t)(b * 2 + pass) * 2 + 0) * 32 + (jt * 4 + w)) * 9) * 512;
      size_t kb1 = ((((size_t)(b * 2 + pass) * 2 + 1) * 32 + (jt * 4 + w)) * 9) * 512;
      f32x4 sRR = f32x4{0.f, 0.f, 0.f, 0.f};
      f32x4 sII = f32x4{0.f, 0.f, 0.f, 0.f};
      f32x4 sRI = f32x4{0.f, 0.f, 0.f, 0.f};
      f32x4 sIR = f32x4{0.f, 0.f, 0.f, 0.f};
#pragma unroll
      for (int ec = 0; ec < 9; ++ec) {
        f16x8 bKr = *(const f16x8*)(Kpack + kb0 + (size_t)ec * 512 + L * 8);
        f16x8 bKi = *(const f16x8*)(Kpack + kb1 + (size_t)ec * 512 + L * 8);
        sRR = __builtin_amdgcn_mfma_f32_16x16x32_f16(Qf[0][ec], bKr, sRR, 0, 0, 0);
        sII = __builtin_amdgcn_mfma_f32_16x16x32_f16(Qf[1][ec], bKi, sII, 0, 0, 0);
        sRI = __builtin_amdgcn_mfma_f32_16x16x32_f16(Qf[0][ec], bKi, sRI, 0, 0, 0);
        sIR = __builtin_amdgcn_mfma_f32_16x16x32_f16(Qf[1][ec], bKr, sIR, 0, 0, 0);
      }

      float vr[4], vi[4];
#pragma unroll
      for (int r = 0; r < 4; ++r) {
        vr[r] = sRR[r] - sII[r];
        vi[r] = sRI[r] + sIR[r];
        float m0 = vr[r];
        m0 = fmaxf(m0, __shfl_xor(m0, 1));
        m0 = fmaxf(m0, __shfl_xor(m0, 2));
        m0 = fmaxf(m0, __shfl_xor(m0, 4));
        m0 = fmaxf(m0, __shfl_xor(m0, 8));
        float m1 = vi[r];
        m1 = fmaxf(m1, __shfl_xor(m1, 1));
        m1 = fmaxf(m1, __shfl_xor(m1, 2));
        m1 = fmaxf(m1, __shfl_xor(m1, 4));
        m1 = fmaxf(m1, __shfl_xor(m1, 8));
        if (lc == 0) {
          sMax[0][q * 4 + r][w] = m0;
          sMax[1][q * 4 + r][w] = m1;
        }
      }
      __syncthreads();  // publish per-wave maxes

      float fac_r[4], fac_i[4];
#pragma unroll
      for (int r = 0; r < 4; ++r) {
        int row = q * 4 + r;
        {
          f32x4 g = *(const f32x4*)&sMax[0][row][0];
          float mt = fmaxf(fmaxf(g[0], g[1]), fmaxf(g[2], g[3]));
          float mn = fmaxf(m_r[r], mt);
          fac_r[r] = __expf(m_r[r] - mn);
          m_r[r] = mn;
          float u = __expf(vr[r] - mn);
          sP[0][row][w * 16 + lc] = (_Float16)u;
          float su = u;
          su += __shfl_xor(su, 1);
          su += __shfl_xor(su, 2);
          su += __shfl_xor(su, 4);
          su += __shfl_xor(su, 8);
          if (lc == 0) sSum[0][row][w] = su;
        }
        {
          f32x4 g = *(const f32x4*)&sMax[1][row][0];
          float mt = fmaxf(fmaxf(g[0], g[1]), fmaxf(g[2], g[3]));
          float mn = fmaxf(m_i[r], mt);
          fac_i[r] = __expf(m_i[r] - mn);
          m_i[r] = mn;
          float u = __expf(vi[r] - mn);
          sP[1][row][w * 16 + lc] = (_Float16)u;
          float su = u;
          su += __shfl_xor(su, 1);
          su += __shfl_xor(su, 2);
          su += __shfl_xor(su, 4);
          su += __shfl_xor(su, 8);
          if (lc == 0) sSum[1][row][w] = su;
        }
      }
      __syncthreads();  // publish P tiles + per-wave sums

#pragma unroll
      for (int r = 0; r < 4; ++r) {
        int row = q * 4 + r;
        f32x4 s0 = *(const f32x4*)&sSum[0][row][0];
        l_r[r] = l_r[r] * fac_r[r] + (s0[0] + s0[1] + s0[2] + s0[3]);
        f32x4 s1 = *(const f32x4*)&sSum[1][row][0];
        l_i[r] = l_i[r] * fac_i[r] + (s1[0] + s1[1] + s1[2] + s1[3]);
      }

      // ---- PV: A-frags (16x16x32) from sP, B-frags coalesced from Vpack ----
      f16x8 aPr[2], aPi[2];
#pragma unroll
      for (int ks = 0; ks < 2; ++ks) {
        aPr[ks] = *(const f16x8*)&sP[0][lc][ks * 32 + q * 8];
        aPi[ks] = *(const f16x8*)&sP[1][lc][ks * 32 + q * 8];
      }
#pragma unroll
      for (int ti = 0; ti < 5; ++ti) {
        if (ti < nt) {
          int et = t0 + ti;
#pragma unroll
          for (int r = 0; r < 4; ++r) {
            accRR[ti][r] *= fac_r[r]; accRI[ti][r] *= fac_r[r];
            accIR[ti][r] *= fac_i[r]; accII[ti][r] *= fac_i[r];
          }
#pragma unroll
          for (int ks = 0; ks < 2; ++ks) {
            size_t vb = (((size_t)(b * 2 + 0) * 17 + et) * 16 + (jt * 2 + ks)) * 512;
            size_t vb2 = (((size_t)(b * 2 + 1) * 17 + et) * 16 + (jt * 2 + ks)) * 512;
            f16x8 bVr = *(const f16x8*)(Vpack + vb + L * 8);
            f16x8 bVi = *(const f16x8*)(Vpack + vb2 + L * 8);
            accRR[ti] = __builtin_amdgcn_mfma_f32_16x16x32_f16(aPr[ks], bVr, accRR[ti], 0, 0, 0);
            accRI[ti] = __builtin_amdgcn_mfma_f32_16x16x32_f16(aPr[ks], bVi, accRI[ti], 0, 0, 0);
            accIR[ti] = __builtin_amdgcn_mfma_f32_16x16x32_f16(aPi[ks], bVr, accIR[ti], 0, 0, 0);
            accII[ti] = __builtin_amdgcn_mfma_f32_16x16x32_f16(aPi[ks], bVi, accII[ti], 0, 0, 0);
          }
        }
      }
      __syncthreads();  // sP reuse next chunk
    }

    // ---- finalize pass (INV_S compensates V pre-scaling) ----
#pragma unroll
    for (int r = 0; r < 4; ++r) {
      float ir = INV_S / l_r[r];
      float ii = INV_S / l_i[r];
#pragma unroll
      for (int ti = 0; ti < 5; ++ti) {
        if (ti < nt) {
          outR[ti][r] += accRR[ti][r] * ir - accII[ti][r] * ii;
          outI[ti][r] += accRI[ti][r] * ir + accIR[ti][r] * ii;
        }
      }
    }
  }

  // ---- store OXh f16 rows into LHf[.][528..1056) ----
  _Float16* obase = OXh + (size_t)(b * 512 + rt * 16) * LD16 + OXOFF;
#pragma unroll
  for (int ti = 0; ti < 5; ++ti) {
    if (ti < nt) {
      int e = (t0 + ti) * 16 + lc;
      if (e < 257) {
#pragma unroll
        for (int r = 0; r < 4; ++r) {
          _Float16* dst = obase + (size_t)(q * 4 + r) * LD16;
          dst[e] = (_Float16)outR[ti][r];
          dst[264 + e] = (_Float16)outI[ti][r];
        }
      }
    }
  }
}

// ---------------- MFMA f16 GEMM: out = OXh @ iDt ----------------
// M=32768, N=512 (8 tiles), K=528 (pad 544). A = LHf+OXOFF (f16, ld 1056).

__global__ __launch_bounds__(256) void gemm_irfft(
    const _Float16* __restrict__ LHf, const _Float16* __restrict__ iDt,
    float* __restrict__ out) {
  __shared__ __align__(16) char lds[33792];
  _Float16* As = (_Float16*)lds;              // [128][40]
  _Float16* Bs = (_Float16*)(lds + 10240);    // [64][40]
  float* CL = (float*)lds;                    // [128][66]

  int t = threadIdx.x;
  int w = t >> 6, L = t & 63, q = L >> 4, lc = L & 15;
  int row0 = blockIdx.y * 128;
  int n0 = blockIdx.x * 64;

  const f16x8 zero8 = {(_Float16)0, (_Float16)0, (_Float16)0, (_Float16)0,
                       (_Float16)0, (_Float16)0, (_Float16)0, (_Float16)0};

  f32x4 acc[2][4];
#pragma unroll
  for (int i = 0; i < 2; ++i)
#pragma unroll
    for (int j = 0; j < 4; ++j) acc[i][j] = f32x4{0.f, 0.f, 0.f, 0.f};

  for (int k0 = 0; k0 < 544; k0 += 32) {
    {
      int m = t >> 1, half = t & 1;
      int kk = k0 + half * 16;
      f16x8 h0, h1;
      if (kk < 528) {
        const _Float16* src = LHf + (size_t)(row0 + m) * LD16 + OXOFF + kk;
        h0 = *(const f16x8*)(src);
        h1 = *(const f16x8*)(src + 8);
      } else {
        h0 = zero8; h1 = zero8;
      }
      *(f16x8*)(As + m * 40 + half * 16) = h0;
      *(f16x8*)(As + m * 40 + half * 16 + 8) = h1;
    }
    {
      int row = t >> 2, ch = t & 3;
      f16x8 bv = *(const f16x8*)(iDt + (size_t)(n0 + row) * 544 + k0 + ch * 8);
      *(f16x8*)(Bs + row * 40 + ch * 8) = bv;
    }
    __syncthreads();
#pragma unroll
    for (int sub = 0; sub < 2; ++sub) {
      f16x8 af = *(const f16x8*)(As + (w * 32 + sub * 16 + lc) * 40 + q * 8);
#pragma unroll
      for (int ns = 0; ns < 4; ++ns) {
        f16x8 bf = *(const f16x8*)(Bs + (ns * 16 + lc) * 40 + q * 8);
        acc[sub][ns] = __builtin_amdgcn_mfma_f32_16x16x32_f16(af, bf, acc[sub][ns], 0, 0, 0);
      }
    }
    __syncthreads();
  }

#pragma unroll
  for (int sub = 0; sub < 2; ++sub)
#pragma unroll
    for (int ns = 0; ns < 4; ++ns)
#pragma unroll
      for (int r = 0; r < 4; ++r)
        CL[(w * 32 + sub * 16 + q * 4 + r) * 66 + ns * 16 + lc] = acc[sub][ns][r];
  __syncthreads();

#pragma unroll
  for (int rep = 0; rep < 8; ++rep) {
    int idx = rep * 256 + t;
    int row = idx >> 4;
    int c4 = idx & 15;
    f32x4 v = *(const f32x4*)(CL + row * 66 + c4 * 4);
    float4 o = {v[0], v[1], v[2], v[3]};
    *(float4*)(out + (size_t)(row0 + row) * 512 + n0 + c4 * 4) = o;
  }
}

// ---------------- launch ----------------

extern "C" void kernel_launch(void* const* d_in, const int* in_sizes, int n_in,
                              void* d_out, int out_size, void* d_ws, size_t ws_size,
                              hipStream_t stream) {
  const float* x   = (const float*)d_in[0];
  const float* l1r = (const float*)d_in[1];
  const float* l1i = (const float*)d_in[2];
  const float* h1r = (const float*)d_in[3];
  const float* h1i = (const float*)d_in[4];
  const float* lbr = (const float*)d_in[5];
  const float* lbi = (const float*)d_in[6];
  const float* hbr = (const float*)d_in[7];
  const float* hbi = (const float*)d_in[8];
  float* out = (float*)d_out;

  _Float16* ws = (_Float16*)d_ws;
  size_t off = 0;
  _Float16* LHf = ws + off;   off += (size_t)32768 * LD16;        // 69.2 MB
  _Float16* Kpack = ws + off; off += (size_t)73728 * 512;         // 75.5 MB
  _Float16* Vpack = ws + off; off += (size_t)64 * 2 * 17 * 16 * 512;  // 35.7 MB
  _Float16* Wt = ws + off;    off += (size_t)1088 * 512;          // 1.1 MB
  _Float16* iDt = ws + off;   off += (size_t)512 * 544;           // 0.6 MB

  hipMemsetAsync(LHf, 0, (size_t)32768 * LD16 * 2, stream);

  build_W<<<1088, 256, 0, stream>>>(l1r, l1i, h1r, h1i, Wt);
  build_idt<<<(512 * 544 + 255) / 256, 256, 0, stream>>>(iDt);

  gemm_main<<<dim3(17, 256), 256, 0, stream>>>(x, Wt, lbr, lbi, hbr, hbi, LHf);
  repack_K<<<73728 / 4, 256, 0, stream>>>(LHf, Kpack);
  repack_V<<<64 * 2 * 17, 256, 0, stream>>>(LHf, Vpack);
  attn_mfma3<<<2048, 256, 0, stream>>>(LHf, Kpack, Vpack, LHf);
  gemm_irfft<<<dim3(8, 256), 256, 0, stream>>>(LHf, iDt, out);
}